// Round 3
// baseline (1026.352 us; speedup 1.0000x reference)
//
#include <hip/hip_runtime.h>
#include <stdint.h>
#include <math.h>

// ---------------------------------------------------------------------------
// Fused transformer block w/ linear attention, bf16 MFMA GEMMs (m97 structure)
//   B=4, N=4096 (TOK=16384 tokens), C=1024, H=16, d=64, HIDDEN=4096
// GEMM: 128x128 tile, BK=32, 4 waves, 4x4 mfma_f32_16x16x32_bf16 per wave,
//       global_load_lds(16B) staging, unpadded LDS.
// Workspace plan (ws assumed >= 256 MiB; we use 248.5 MiB):
//   weights bf16 24.9MB | kvt+ksm 0.54MB | x2 fp32 64MB | h12 32MB |
//   pool 128MB = qbuf|ktb|vtb|abuf ; pkv/pks overlay abuf (disjoint lifetime);
//   h3 (gelu out, 128MB) overlays the whole pool.
// ---------------------------------------------------------------------------

#define TOK   16384
#define CDIM  1024
#define NHEAD 16
#define HD    64
#define SEQ   4096
#define NBH   64
#define HID   4096

typedef unsigned short u16;
typedef __attribute__((ext_vector_type(8))) short bf16x8;
typedef __attribute__((ext_vector_type(4))) float f32x4;
typedef __attribute__((ext_vector_type(4))) unsigned short u16x4;

__device__ __forceinline__ u16 f2bf(float f) {
  union { float f; uint32_t u; } c; c.f = f;
  uint32_t u = c.u;
  return (u16)((u + 0x7fffu + ((u >> 16) & 1u)) >> 16);  // RNE
}
__device__ __forceinline__ float bf2f(u16 h) {
  union { uint32_t u; float f; } c; c.u = ((uint32_t)h) << 16;
  return c.f;
}

typedef const __attribute__((address_space(1))) uint32_t* gas_t;
typedef __attribute__((address_space(3))) uint32_t* las_t;
__device__ __forceinline__ void gl_lds16(const u16* g, u16* l) {
  __builtin_amdgcn_global_load_lds((gas_t)g, (las_t)l, 16, 0, 0);
}

// ---------------- weight convert fp32 -> bf16 (vectorized) -----------------
__global__ __launch_bounds__(256) void cvt_kernel(const float* __restrict__ in,
                                                  u16* __restrict__ out, int n4) {
  int i = blockIdx.x * 256 + threadIdx.x;
  if (i < n4) {
    float4 v = ((const float4*)in)[i];
    u16x4 o;
    o.x = f2bf(v.x); o.y = f2bf(v.y); o.z = f2bf(v.z); o.w = f2bf(v.w);
    ((u16x4*)out)[i] = o;
  }
}

// ---------------- LayerNorm (row of 1024), fp32 in -> bf16 out -------------
__global__ __launch_bounds__(256) void ln_kernel(const float* __restrict__ xin,
                                                 const float* __restrict__ g,
                                                 const float* __restrict__ b,
                                                 u16* __restrict__ out) {
  int row = blockIdx.x;
  int t = threadIdx.x;
  const float4* xr = (const float4*)(xin + (size_t)row * CDIM);
  float4 v = xr[t];
  float s  = v.x + v.y + v.z + v.w;
  float s2 = v.x * v.x + v.y * v.y + v.z * v.z + v.w * v.w;
#pragma unroll
  for (int off = 32; off > 0; off >>= 1) {
    s  += __shfl_down(s, off);
    s2 += __shfl_down(s2, off);
  }
  __shared__ float as_[4], bs_[4];
  if ((t & 63) == 0) { as_[t >> 6] = s; bs_[t >> 6] = s2; }
  __syncthreads();
  s  = as_[0] + as_[1] + as_[2] + as_[3];
  s2 = bs_[0] + bs_[1] + bs_[2] + bs_[3];
  float mu  = s * (1.0f / CDIM);
  float var = s2 * (1.0f / CDIM) - mu * mu;
  float rs  = rsqrtf(var + 1e-5f);
  float4 gv = ((const float4*)g)[t];
  float4 bv = ((const float4*)b)[t];
  u16x4 o;
  o.x = f2bf((v.x - mu) * rs * gv.x + bv.x);
  o.y = f2bf((v.y - mu) * rs * gv.y + bv.y);
  o.z = f2bf((v.z - mu) * rs * gv.z + bv.z);
  o.w = f2bf((v.w - mu) * rs * gv.w + bv.w);
  ((u16x4*)(out + (size_t)row * CDIM))[t] = o;
}

// ---------------- main GEMM: A[M,K] x W[N,K]^T, fused epilogues ------------
enum { M_QKV = 0, M_PROJ = 1, M_FC1 = 2, M_FC2 = 3 };

template <int MODE>
__global__ __launch_bounds__(256) void gemm_bt(const u16* __restrict__ A,
                                               const u16* __restrict__ W, int K,
                                               void* __restrict__ o0,
                                               void* __restrict__ o1,
                                               void* __restrict__ o2,
                                               const float* __restrict__ bias,
                                               const float* __restrict__ resid) {
  __shared__ __align__(16) u16 Als[128 * 32];
  __shared__ __align__(16) u16 Bls[128 * 32];
  const int t = threadIdx.x;
  const int l = t & 63, w = t >> 6;
  const int m0 = blockIdx.x * 128, n0 = blockIdx.y * 128;
  const int wm = (w >> 1) * 64, wn = (w & 1) * 64;
  const int fr = l & 15, qq = l >> 4;

  f32x4 acc[4][4] = {};

  const u16* Ab = A + (size_t)m0 * K;
  const u16* Wb = W + (size_t)n0 * K;

  for (int k0 = 0; k0 < K; k0 += 32) {
#pragma unroll
    for (int i = 0; i < 2; ++i) {
      int p = i * 256 + t;           // chunk id: row = p>>2, 16B chunk = p&3
      int row = p >> 2, ch = p & 3;
      gl_lds16(Ab + (size_t)row * K + k0 + ch * 8, &Als[p * 8]);
      gl_lds16(Wb + (size_t)row * K + k0 + ch * 8, &Bls[p * 8]);
    }
    __builtin_amdgcn_s_waitcnt(0);
    __syncthreads();
    bf16x8 af[4], bfv[4];
#pragma unroll
    for (int i = 0; i < 4; ++i) {
      af[i]  = *(const bf16x8*)&Als[(wm + i * 16 + fr) * 32 + qq * 8];
      bfv[i] = *(const bf16x8*)&Bls[(wn + i * 16 + fr) * 32 + qq * 8];
    }
#pragma unroll
    for (int i = 0; i < 4; ++i)
#pragma unroll
      for (int j = 0; j < 4; ++j)
        acc[i][j] = __builtin_amdgcn_mfma_f32_16x16x32_bf16(af[i], bfv[j], acc[i][j], 0, 0, 0);
    __syncthreads();
  }

  // epilogue: D element (row=(l>>4)*4+reg, col=l&15) per 16x16 tile
#pragma unroll
  for (int i = 0; i < 4; ++i) {
#pragma unroll
    for (int j = 0; j < 4; ++j) {
      int gm0 = m0 + wm + i * 16 + qq * 4;
      int go  = n0 + wn + j * 16 + fr;
#pragma unroll
      for (int r = 0; r < 4; ++r) {
        int gm = gm0 + r;
        float v = acc[i][j][r];
        if constexpr (MODE == M_QKV) {
          int sect = go >> 10, c = go & 1023;
          int h = c >> 6, dd = c & 63;
          int b = gm >> 12, n = gm & 4095;
          int bh = b * NHEAD + h;
          if (sect == 0) {          // q = elu(v)+1, layout [bh][n][d]
            float qv = v > 0.f ? v + 1.f : __expf(v);
            ((u16*)o0)[((size_t)bh * SEQ + n) * HD + dd] = f2bf(qv);
          } else if (sect == 1) {   // k = elu(v)+1, transposed [bh][d][n]
            float kk = v > 0.f ? v + 1.f : __expf(v);
            ((u16*)o1)[((size_t)bh * HD + dd) * SEQ + n] = f2bf(kk);
          } else {                  // v, transposed [bh][d][n]
            ((u16*)o2)[((size_t)bh * HD + dd) * SEQ + n] = f2bf(v);
          }
        } else if constexpr (MODE == M_PROJ) {
          ((float*)o0)[(size_t)gm * CDIM + go] = v + bias[go] + resid[(size_t)gm * CDIM + go];
        } else if constexpr (MODE == M_FC1) {
          float u = v + bias[go];
          float ge = 0.5f * u * (1.0f + erff(u * 0.70710678118654752f));
          ((u16*)o0)[(size_t)gm * HID + go] = f2bf(ge);
        } else {  // M_FC2
          ((float*)o0)[(size_t)gm * CDIM + go] = v + bias[go] + resid[(size_t)gm * CDIM + go];
        }
      }
    }
  }
}

// ------- kv state: partial kvT[e][d] = sum_n v[n,e]*k[n,d], per n-chunk -----
__global__ __launch_bounds__(256) void kv_stage1(const u16* __restrict__ kt,
                                                 const u16* __restrict__ vt,
                                                 float* __restrict__ pkv,
                                                 float* __restrict__ pks) {
  int ch = blockIdx.x, bh = blockIdx.y;
  int t = threadIdx.x, l = t & 63, w = t >> 6;
  int fr = l & 15, qq = l >> 4;
  int nb = ch * 512;
  const u16* vb = vt + (size_t)bh * HD * SEQ;
  const u16* kb = kt + (size_t)bh * HD * SEQ;
  int e0 = (w >> 1) * 32, d0 = (w & 1) * 32;
  f32x4 acc[2][2] = {};
  for (int kk = 0; kk < 512; kk += 32) {
    bf16x8 af[2], bfv[2];
#pragma unroll
    for (int i = 0; i < 2; ++i)
      af[i] = *(const bf16x8*)(vb + (size_t)(e0 + i * 16 + fr) * SEQ + nb + kk + qq * 8);
#pragma unroll
    for (int j = 0; j < 2; ++j)
      bfv[j] = *(const bf16x8*)(kb + (size_t)(d0 + j * 16 + fr) * SEQ + nb + kk + qq * 8);
#pragma unroll
    for (int i = 0; i < 2; ++i)
#pragma unroll
      for (int j = 0; j < 2; ++j)
        acc[i][j] = __builtin_amdgcn_mfma_f32_16x16x32_bf16(af[i], bfv[j], acc[i][j], 0, 0, 0);
  }
  float* pout = pkv + ((size_t)ch * NBH + bh) * 4096;
#pragma unroll
  for (int i = 0; i < 2; ++i)
#pragma unroll
    for (int j = 0; j < 2; ++j)
#pragma unroll
      for (int r = 0; r < 4; ++r) {
        int e = e0 + i * 16 + qq * 4 + r;
        int d = d0 + j * 16 + fr;
        pout[e * 64 + d] = acc[i][j][r];
      }
  // partial ksum over this n-chunk
  __shared__ float ksp[256];
  {
    int d = t & 63, part = t >> 6;
    const u16* kr = kb + (size_t)d * SEQ + nb + part * 128;
    float s = 0;
    for (int n = 0; n < 128; ++n) s += bf2f(kr[n]);
    ksp[t] = s;
  }
  __syncthreads();
  if (t < 64) {
    float s = ksp[t] + ksp[64 + t] + ksp[128 + t] + ksp[192 + t];
    pks[((size_t)ch * NBH + bh) * 64 + t] = s;
  }
}

__global__ __launch_bounds__(256) void kv_reduce(const float* __restrict__ pkv,
                                                 const float* __restrict__ pks,
                                                 u16* __restrict__ kvt,
                                                 float* __restrict__ ksm) {
  int bh = blockIdx.x, t = threadIdx.x;
  for (int ii = 0; ii < 16; ++ii) {
    int idx = ii * 256 + t;
    float s = 0;
#pragma unroll
    for (int c = 0; c < 8; ++c) s += pkv[((size_t)c * NBH + bh) * 4096 + idx];
    kvt[(size_t)bh * 4096 + idx] = f2bf(s);
  }
  if (t < 64) {
    float s = 0;
#pragma unroll
    for (int c = 0; c < 8; ++c) s += pks[((size_t)c * NBH + bh) * 64 + t];
    ksm[bh * 64 + t] = s;
  }
}

// ------- attn: out[n,e] = (sum_d q[n,d]*kvT[e,d]) * z[n], -> [b,n,c] bf16 ---
__global__ __launch_bounds__(256) void attn_kernel(const u16* __restrict__ qb,
                                                   const u16* __restrict__ kvt,
                                                   const float* __restrict__ ksm,
                                                   u16* __restrict__ ab) {
  int nblk = blockIdx.x, bh = blockIdx.y;
  int n0 = nblk * 128;
  int t = threadIdx.x, l = t & 63, w = t >> 6;
  int fr = l & 15, qq = l >> 4;
  __shared__ float ksh[64];
  __shared__ float part[256];
  __shared__ float zsh[128];
  if (t < 64) ksh[t] = ksm[bh * 64 + t];
  __syncthreads();
  {
    int rr = t >> 1, hf = t & 1;
    const u16* qr = qb + ((size_t)bh * SEQ + n0 + rr) * HD + hf * 32;
    float s = 0;
#pragma unroll
    for (int d = 0; d < 32; ++d) s += bf2f(qr[d]) * ksh[hf * 32 + d];
    part[t] = s;
  }
  __syncthreads();
  if (t < 128) zsh[t] = 1.0f / (part[2 * t] + part[2 * t + 1] + 1e-6f);
  __syncthreads();

  f32x4 acc[2][4] = {};
  const u16* qbase = qb + ((size_t)bh * SEQ + n0) * HD;
  const u16* kvb = kvt + (size_t)bh * 4096;
#pragma unroll
  for (int ks = 0; ks < 64; ks += 32) {
    bf16x8 af[2], bfv[4];
#pragma unroll
    for (int i = 0; i < 2; ++i)
      af[i] = *(const bf16x8*)(qbase + (size_t)(w * 32 + i * 16 + fr) * HD + ks + qq * 8);
#pragma unroll
    for (int j = 0; j < 4; ++j)
      bfv[j] = *(const bf16x8*)(kvb + (size_t)(j * 16 + fr) * HD + ks + qq * 8);
#pragma unroll
    for (int i = 0; i < 2; ++i)
#pragma unroll
      for (int j = 0; j < 4; ++j)
        acc[i][j] = __builtin_amdgcn_mfma_f32_16x16x32_bf16(af[i], bfv[j], acc[i][j], 0, 0, 0);
  }
  int b = bh >> 4, h = bh & 15;
#pragma unroll
  for (int i = 0; i < 2; ++i)
#pragma unroll
    for (int j = 0; j < 4; ++j)
#pragma unroll
      for (int r = 0; r < 4; ++r) {
        int rl = w * 32 + i * 16 + qq * 4 + r;
        int n = n0 + rl;
        int e = j * 16 + fr;
        float v = acc[i][j][r] * zsh[rl];
        ab[((size_t)(b * SEQ + n)) * CDIM + h * HD + e] = f2bf(v);
      }
}

// ---------------------------------------------------------------------------
extern "C" void kernel_launch(void* const* d_in, const int* in_sizes, int n_in,
                              void* d_out, int out_size, void* d_ws, size_t ws_size,
                              hipStream_t stream) {
  (void)in_sizes; (void)n_in; (void)out_size; (void)ws_size;
  const float* x     = (const float*)d_in[0];
  const float* n1g   = (const float*)d_in[1];
  const float* n1b   = (const float*)d_in[2];
  const float* qkvw  = (const float*)d_in[3];
  const float* projw = (const float*)d_in[4];
  const float* projb = (const float*)d_in[5];
  const float* n2g   = (const float*)d_in[6];
  const float* n2b   = (const float*)d_in[7];
  const float* fc1w  = (const float*)d_in[8];
  const float* fc1b  = (const float*)d_in[9];
  const float* fc2w  = (const float*)d_in[10];
  const float* fc2b  = (const float*)d_in[11];
  float* out = (float*)d_out;

  char* ws = (char*)d_ws;
  size_t off = 0;
  auto alloc = [&](size_t bytes) {
    void* p = ws + off;
    off += (bytes + 255) & ~(size_t)255;
    return p;
  };
  // --- persistent-lifetime allocations (248.5 MiB total incl. pool) ---
  u16*  wq   = (u16*)alloc((size_t)3 * CDIM * CDIM * 2);   // 6 MB  qkv_w bf16
  u16*  wp   = (u16*)alloc((size_t)CDIM * CDIM * 2);       // 2 MB  proj_w bf16
  u16*  w1   = (u16*)alloc((size_t)HID * CDIM * 2);        // 8 MB  fc1_w bf16
  u16*  w2   = (u16*)alloc((size_t)CDIM * HID * 2);        // 8 MB  fc2_w bf16
  u16*  kvt  = (u16*)alloc((size_t)NBH * 4096 * 2);        // 512KB kvT bf16
  float* ksm = (float*)alloc((size_t)NBH * 64 * 4);        // 16 KB ksum
  float* x2  = (float*)alloc((size_t)TOK * CDIM * 4);      // 64 MB x + attn (fp32)
  u16*  h12  = (u16*)alloc((size_t)TOK * CDIM * 2);        // 32 MB ln1 out, later ln2 out
  // --- 128 MB pool with overlaid lifetimes ---
  u16*  qbuf = (u16*)alloc((size_t)TOK * CDIM * 2);        // 32 MB phi(q) [bh][n][d]
  u16*  ktb  = (u16*)alloc((size_t)TOK * CDIM * 2);        // 32 MB phi(k) [bh][d][n]
  u16*  vtb  = (u16*)alloc((size_t)TOK * CDIM * 2);        // 32 MB v      [bh][d][n]
  u16*  abuf = (u16*)alloc((size_t)TOK * CDIM * 2);        // 32 MB attn out [b,n,c]
  // pkv/pks overlay abuf: dead before attn_kernel writes abuf
  float* pkv = (float*)abuf;                               // 8 MB  partial kv
  float* pks = (float*)(abuf + (size_t)8 * NBH * 4096 * 2);// 128KB partial ksum
  u16*  h3   = qbuf;  // 128 MB gelu out: reuses qbuf..abuf (all dead after proj)

  // weights fp32 -> bf16
  cvt_kernel<<<dim3(3 * CDIM * CDIM / 1024), 256, 0, stream>>>(qkvw, wq, 3 * CDIM * CDIM / 4);
  cvt_kernel<<<dim3(CDIM * CDIM / 1024),     256, 0, stream>>>(projw, wp, CDIM * CDIM / 4);
  cvt_kernel<<<dim3(HID * CDIM / 1024),      256, 0, stream>>>(fc1w, w1, HID * CDIM / 4);
  cvt_kernel<<<dim3(CDIM * HID / 1024),      256, 0, stream>>>(fc2w, w2, CDIM * HID / 4);

  ln_kernel<<<dim3(TOK), 256, 0, stream>>>(x, n1g, n1b, h12);
  gemm_bt<M_QKV><<<dim3(TOK / 128, 3 * CDIM / 128), 256, 0, stream>>>(
      h12, wq, CDIM, qbuf, ktb, vtb, nullptr, nullptr);
  kv_stage1<<<dim3(8, NBH), 256, 0, stream>>>(ktb, vtb, pkv, pks);
  kv_reduce<<<dim3(NBH), 256, 0, stream>>>(pkv, pks, kvt, ksm);
  attn_kernel<<<dim3(SEQ / 128, NBH), 256, 0, stream>>>(qbuf, kvt, ksm, abuf);
  gemm_bt<M_PROJ><<<dim3(TOK / 128, CDIM / 128), 256, 0, stream>>>(
      abuf, wp, CDIM, x2, nullptr, nullptr, projb, x);
  ln_kernel<<<dim3(TOK), 256, 0, stream>>>(x2, n2g, n2b, h12);
  gemm_bt<M_FC1><<<dim3(TOK / 128, HID / 128), 256, 0, stream>>>(
      h12, w1, CDIM, h3, nullptr, nullptr, fc1b, nullptr);
  gemm_bt<M_FC2><<<dim3(TOK / 128, CDIM / 128), 256, 0, stream>>>(
      h3, w2, HID, out, nullptr, nullptr, fc2b, x2);
}

// Round 4
// 996.271 us; speedup vs baseline: 1.0302x; 1.0302x over previous
//
#include <hip/hip_runtime.h>
#include <stdint.h>
#include <math.h>

// ---------------------------------------------------------------------------
// Fused transformer block w/ linear attention, bf16 MFMA GEMMs
//   B=4, N=4096 (TOK=16384 tokens), C=1024, H=16, d=64, HIDDEN=4096
// R4: GEMM core switched to mfma_f32_32x32x16_bf16 (2x2 tiles/wave, 8 MFMA +
//     8 ds_read_b128 per BK=32 iter); FC1 gelu now sigmoid-form tanh approx
//     (no libm erff). Layouts per guide: A/B frag m|n=lane&31, k=(lane>>5)*8+j;
//     C/D col=lane&31, row=(reg&3)+8*(reg>>2)+4*(lane>>5).
// Workspace: 248.5 MiB, pkv/pks overlay abuf (disjoint lifetimes).
// ---------------------------------------------------------------------------

#define TOK   16384
#define CDIM  1024
#define NHEAD 16
#define HD    64
#define SEQ   4096
#define NBH   64
#define HID   4096

typedef unsigned short u16;
typedef __attribute__((ext_vector_type(8))) short bf16x8;
typedef __attribute__((ext_vector_type(4))) float f32x4;
typedef __attribute__((ext_vector_type(16))) float f32x16;
typedef __attribute__((ext_vector_type(4))) unsigned short u16x4;

__device__ __forceinline__ u16 f2bf(float f) {
  union { float f; uint32_t u; } c; c.f = f;
  uint32_t u = c.u;
  return (u16)((u + 0x7fffu + ((u >> 16) & 1u)) >> 16);  // RNE
}
__device__ __forceinline__ float bf2f(u16 h) {
  union { uint32_t u; float f; } c; c.u = ((uint32_t)h) << 16;
  return c.f;
}
__device__ __forceinline__ float gelu_fast(float u) {
  // 0.5u(1+tanh(0.79788456(u+0.044715u^3))) == u*sigmoid(1.59576912(u+...))
  float y = 1.5957691216f * (u + 0.044715f * u * u * u);
  return u * __builtin_amdgcn_rcpf(1.0f + __expf(-y));
}

typedef const __attribute__((address_space(1))) uint32_t* gas_t;
typedef __attribute__((address_space(3))) uint32_t* las_t;
__device__ __forceinline__ void gl_lds16(const u16* g, u16* l) {
  __builtin_amdgcn_global_load_lds((gas_t)g, (las_t)l, 16, 0, 0);
}

// ---------------- weight convert fp32 -> bf16 (vectorized) -----------------
__global__ __launch_bounds__(256) void cvt_kernel(const float* __restrict__ in,
                                                  u16* __restrict__ out, int n4) {
  int i = blockIdx.x * 256 + threadIdx.x;
  if (i < n4) {
    float4 v = ((const float4*)in)[i];
    u16x4 o;
    o.x = f2bf(v.x); o.y = f2bf(v.y); o.z = f2bf(v.z); o.w = f2bf(v.w);
    ((u16x4*)out)[i] = o;
  }
}

// ---------------- LayerNorm (row of 1024), fp32 in -> bf16 out -------------
__global__ __launch_bounds__(256) void ln_kernel(const float* __restrict__ xin,
                                                 const float* __restrict__ g,
                                                 const float* __restrict__ b,
                                                 u16* __restrict__ out) {
  int row = blockIdx.x;
  int t = threadIdx.x;
  const float4* xr = (const float4*)(xin + (size_t)row * CDIM);
  float4 v = xr[t];
  float s  = v.x + v.y + v.z + v.w;
  float s2 = v.x * v.x + v.y * v.y + v.z * v.z + v.w * v.w;
#pragma unroll
  for (int off = 32; off > 0; off >>= 1) {
    s  += __shfl_down(s, off);
    s2 += __shfl_down(s2, off);
  }
  __shared__ float as_[4], bs_[4];
  if ((t & 63) == 0) { as_[t >> 6] = s; bs_[t >> 6] = s2; }
  __syncthreads();
  s  = as_[0] + as_[1] + as_[2] + as_[3];
  s2 = bs_[0] + bs_[1] + bs_[2] + bs_[3];
  float mu  = s * (1.0f / CDIM);
  float var = s2 * (1.0f / CDIM) - mu * mu;
  float rs  = rsqrtf(var + 1e-5f);
  float4 gv = ((const float4*)g)[t];
  float4 bv = ((const float4*)b)[t];
  u16x4 o;
  o.x = f2bf((v.x - mu) * rs * gv.x + bv.x);
  o.y = f2bf((v.y - mu) * rs * gv.y + bv.y);
  o.z = f2bf((v.z - mu) * rs * gv.z + bv.z);
  o.w = f2bf((v.w - mu) * rs * gv.w + bv.w);
  ((u16x4*)(out + (size_t)row * CDIM))[t] = o;
}

// ---------------- main GEMM: A[M,K] x W[N,K]^T, fused epilogues ------------
enum { M_QKV = 0, M_PROJ = 1, M_FC1 = 2, M_FC2 = 3 };

template <int MODE>
__global__ __launch_bounds__(256) void gemm_bt(const u16* __restrict__ A,
                                               const u16* __restrict__ W, int K,
                                               void* __restrict__ o0,
                                               void* __restrict__ o1,
                                               void* __restrict__ o2,
                                               const float* __restrict__ bias,
                                               const float* __restrict__ resid) {
  __shared__ __align__(16) u16 Als[128 * 32];
  __shared__ __align__(16) u16 Bls[128 * 32];
  const int t = threadIdx.x;
  const int l = t & 63, w = t >> 6;
  const int m0 = blockIdx.x * 128, n0 = blockIdx.y * 128;
  const int wm = (w >> 1) * 64, wn = (w & 1) * 64;
  const int ml = l & 31, kh = l >> 5;   // 32x32 frag: m|n = lane&31, k-half = lane>>5

  f32x16 acc[2][2] = {};

  const u16* Ab = A + (size_t)m0 * K;
  const u16* Wb = W + (size_t)n0 * K;

  for (int k0 = 0; k0 < K; k0 += 32) {
#pragma unroll
    for (int i = 0; i < 2; ++i) {
      int p = i * 256 + t;           // chunk id: row = p>>2, 16B chunk = p&3
      int row = p >> 2, ch = p & 3;
      gl_lds16(Ab + (size_t)row * K + k0 + ch * 8, &Als[p * 8]);
      gl_lds16(Wb + (size_t)row * K + k0 + ch * 8, &Bls[p * 8]);
    }
    __builtin_amdgcn_s_waitcnt(0);
    __syncthreads();
    bf16x8 af[2][2], bfv[2][2];
#pragma unroll
    for (int s = 0; s < 2; ++s)
#pragma unroll
      for (int i = 0; i < 2; ++i) {
        af[i][s]  = *(const bf16x8*)&Als[(wm + i * 32 + ml) * 32 + s * 16 + kh * 8];
        bfv[i][s] = *(const bf16x8*)&Bls[(wn + i * 32 + ml) * 32 + s * 16 + kh * 8];
      }
#pragma unroll
    for (int s = 0; s < 2; ++s)
#pragma unroll
      for (int i = 0; i < 2; ++i)
#pragma unroll
        for (int j = 0; j < 2; ++j)
          acc[i][j] = __builtin_amdgcn_mfma_f32_32x32x16_bf16(af[i][s], bfv[j][s],
                                                              acc[i][j], 0, 0, 0);
    __syncthreads();
  }

  // epilogue: D element col=lane&31, row=(r&3)+8*(r>>2)+4*(lane>>5), r in [0,16)
#pragma unroll
  for (int i = 0; i < 2; ++i) {
#pragma unroll
    for (int j = 0; j < 2; ++j) {
      int go = n0 + wn + j * 32 + ml;
#pragma unroll
      for (int r = 0; r < 16; ++r) {
        int gm = m0 + wm + i * 32 + (r & 3) + 8 * (r >> 2) + 4 * kh;
        float v = acc[i][j][r];
        if constexpr (MODE == M_QKV) {
          int sect = go >> 10, c = go & 1023;
          int h = c >> 6, dd = c & 63;
          int b = gm >> 12, n = gm & 4095;
          int bh = b * NHEAD + h;
          if (sect == 0) {          // q = elu(v)+1, layout [bh][n][d]
            float qv = v > 0.f ? v + 1.f : __expf(v);
            ((u16*)o0)[((size_t)bh * SEQ + n) * HD + dd] = f2bf(qv);
          } else if (sect == 1) {   // k = elu(v)+1, transposed [bh][d][n]
            float kk = v > 0.f ? v + 1.f : __expf(v);
            ((u16*)o1)[((size_t)bh * HD + dd) * SEQ + n] = f2bf(kk);
          } else {                  // v, transposed [bh][d][n]
            ((u16*)o2)[((size_t)bh * HD + dd) * SEQ + n] = f2bf(v);
          }
        } else if constexpr (MODE == M_PROJ) {
          ((float*)o0)[(size_t)gm * CDIM + go] = v + bias[go] + resid[(size_t)gm * CDIM + go];
        } else if constexpr (MODE == M_FC1) {
          float u = v + bias[go];
          ((u16*)o0)[(size_t)gm * HID + go] = f2bf(gelu_fast(u));
        } else {  // M_FC2
          ((float*)o0)[(size_t)gm * CDIM + go] = v + bias[go] + resid[(size_t)gm * CDIM + go];
        }
      }
    }
  }
}

// ------- kv state: partial kvT[e][d] = sum_n v[n,e]*k[n,d], per n-chunk -----
__global__ __launch_bounds__(256) void kv_stage1(const u16* __restrict__ kt,
                                                 const u16* __restrict__ vt,
                                                 float* __restrict__ pkv,
                                                 float* __restrict__ pks) {
  int ch = blockIdx.x, bh = blockIdx.y;
  int t = threadIdx.x, l = t & 63, w = t >> 6;
  int fr = l & 15, qq = l >> 4;
  int nb = ch * 512;
  const u16* vb = vt + (size_t)bh * HD * SEQ;
  const u16* kb = kt + (size_t)bh * HD * SEQ;
  int e0 = (w >> 1) * 32, d0 = (w & 1) * 32;
  f32x4 acc[2][2] = {};
  for (int kk = 0; kk < 512; kk += 32) {
    bf16x8 af[2], bfv[2];
#pragma unroll
    for (int i = 0; i < 2; ++i)
      af[i] = *(const bf16x8*)(vb + (size_t)(e0 + i * 16 + fr) * SEQ + nb + kk + qq * 8);
#pragma unroll
    for (int j = 0; j < 2; ++j)
      bfv[j] = *(const bf16x8*)(kb + (size_t)(d0 + j * 16 + fr) * SEQ + nb + kk + qq * 8);
#pragma unroll
    for (int i = 0; i < 2; ++i)
#pragma unroll
      for (int j = 0; j < 2; ++j)
        acc[i][j] = __builtin_amdgcn_mfma_f32_16x16x32_bf16(af[i], bfv[j], acc[i][j], 0, 0, 0);
  }
  float* pout = pkv + ((size_t)ch * NBH + bh) * 4096;
#pragma unroll
  for (int i = 0; i < 2; ++i)
#pragma unroll
    for (int j = 0; j < 2; ++j)
#pragma unroll
      for (int r = 0; r < 4; ++r) {
        int e = e0 + i * 16 + qq * 4 + r;
        int d = d0 + j * 16 + fr;
        pout[e * 64 + d] = acc[i][j][r];
      }
  // partial ksum over this n-chunk
  __shared__ float ksp[256];
  {
    int d = t & 63, part = t >> 6;
    const u16* kr = kb + (size_t)d * SEQ + nb + part * 128;
    float s = 0;
    for (int n = 0; n < 128; ++n) s += bf2f(kr[n]);
    ksp[t] = s;
  }
  __syncthreads();
  if (t < 64) {
    float s = ksp[t] + ksp[64 + t] + ksp[128 + t] + ksp[192 + t];
    pks[((size_t)ch * NBH + bh) * 64 + t] = s;
  }
}

__global__ __launch_bounds__(256) void kv_reduce(const float* __restrict__ pkv,
                                                 const float* __restrict__ pks,
                                                 u16* __restrict__ kvt,
                                                 float* __restrict__ ksm) {
  int bh = blockIdx.x, t = threadIdx.x;
  for (int ii = 0; ii < 16; ++ii) {
    int idx = ii * 256 + t;
    float s = 0;
#pragma unroll
    for (int c = 0; c < 8; ++c) s += pkv[((size_t)c * NBH + bh) * 4096 + idx];
    kvt[(size_t)bh * 4096 + idx] = f2bf(s);
  }
  if (t < 64) {
    float s = 0;
#pragma unroll
    for (int c = 0; c < 8; ++c) s += pks[((size_t)c * NBH + bh) * 64 + t];
    ksm[bh * 64 + t] = s;
  }
}

// ------- attn: out[n,e] = (sum_d q[n,d]*kvT[e,d]) * z[n], -> [b,n,c] bf16 ---
__global__ __launch_bounds__(256) void attn_kernel(const u16* __restrict__ qb,
                                                   const u16* __restrict__ kvt,
                                                   const float* __restrict__ ksm,
                                                   u16* __restrict__ ab) {
  int nblk = blockIdx.x, bh = blockIdx.y;
  int n0 = nblk * 128;
  int t = threadIdx.x, l = t & 63, w = t >> 6;
  int fr = l & 15, qq = l >> 4;
  __shared__ float ksh[64];
  __shared__ float part[256];
  __shared__ float zsh[128];
  if (t < 64) ksh[t] = ksm[bh * 64 + t];
  __syncthreads();
  {
    int rr = t >> 1, hf = t & 1;
    const u16* qr = qb + ((size_t)bh * SEQ + n0 + rr) * HD + hf * 32;
    float s = 0;
#pragma unroll
    for (int d = 0; d < 32; ++d) s += bf2f(qr[d]) * ksh[hf * 32 + d];
    part[t] = s;
  }
  __syncthreads();
  if (t < 128) zsh[t] = 1.0f / (part[2 * t] + part[2 * t + 1] + 1e-6f);
  __syncthreads();

  f32x4 acc[2][4] = {};
  const u16* qbase = qb + ((size_t)bh * SEQ + n0) * HD;
  const u16* kvb = kvt + (size_t)bh * 4096;
#pragma unroll
  for (int ks = 0; ks < 64; ks += 32) {
    bf16x8 af[2], bfv[4];
#pragma unroll
    for (int i = 0; i < 2; ++i)
      af[i] = *(const bf16x8*)(qbase + (size_t)(w * 32 + i * 16 + fr) * HD + ks + qq * 8);
#pragma unroll
    for (int j = 0; j < 4; ++j)
      bfv[j] = *(const bf16x8*)(kvb + (size_t)(j * 16 + fr) * HD + ks + qq * 8);
#pragma unroll
    for (int i = 0; i < 2; ++i)
#pragma unroll
      for (int j = 0; j < 4; ++j)
        acc[i][j] = __builtin_amdgcn_mfma_f32_16x16x32_bf16(af[i], bfv[j], acc[i][j], 0, 0, 0);
  }
  int b = bh >> 4, h = bh & 15;
#pragma unroll
  for (int i = 0; i < 2; ++i)
#pragma unroll
    for (int j = 0; j < 4; ++j)
#pragma unroll
      for (int r = 0; r < 4; ++r) {
        int rl = w * 32 + i * 16 + qq * 4 + r;
        int n = n0 + rl;
        int e = j * 16 + fr;
        float v = acc[i][j][r] * zsh[rl];
        ab[((size_t)(b * SEQ + n)) * CDIM + h * HD + e] = f2bf(v);
      }
}

// ---------------------------------------------------------------------------
extern "C" void kernel_launch(void* const* d_in, const int* in_sizes, int n_in,
                              void* d_out, int out_size, void* d_ws, size_t ws_size,
                              hipStream_t stream) {
  (void)in_sizes; (void)n_in; (void)out_size; (void)ws_size;
  const float* x     = (const float*)d_in[0];
  const float* n1g   = (const float*)d_in[1];
  const float* n1b   = (const float*)d_in[2];
  const float* qkvw  = (const float*)d_in[3];
  const float* projw = (const float*)d_in[4];
  const float* projb = (const float*)d_in[5];
  const float* n2g   = (const float*)d_in[6];
  const float* n2b   = (const float*)d_in[7];
  const float* fc1w  = (const float*)d_in[8];
  const float* fc1b  = (const float*)d_in[9];
  const float* fc2w  = (const float*)d_in[10];
  const float* fc2b  = (const float*)d_in[11];
  float* out = (float*)d_out;

  char* ws = (char*)d_ws;
  size_t off = 0;
  auto alloc = [&](size_t bytes) {
    void* p = ws + off;
    off += (bytes + 255) & ~(size_t)255;
    return p;
  };
  // --- persistent-lifetime allocations (248.5 MiB total incl. pool) ---
  u16*  wq   = (u16*)alloc((size_t)3 * CDIM * CDIM * 2);   // 6 MB  qkv_w bf16
  u16*  wp   = (u16*)alloc((size_t)CDIM * CDIM * 2);       // 2 MB  proj_w bf16
  u16*  w1   = (u16*)alloc((size_t)HID * CDIM * 2);        // 8 MB  fc1_w bf16
  u16*  w2   = (u16*)alloc((size_t)CDIM * HID * 2);        // 8 MB  fc2_w bf16
  u16*  kvt  = (u16*)alloc((size_t)NBH * 4096 * 2);        // 512KB kvT bf16
  float* ksm = (float*)alloc((size_t)NBH * 64 * 4);        // 16 KB ksum
  float* x2  = (float*)alloc((size_t)TOK * CDIM * 4);      // 64 MB x + attn (fp32)
  u16*  h12  = (u16*)alloc((size_t)TOK * CDIM * 2);        // 32 MB ln1 out, later ln2 out
  // --- 128 MB pool with overlaid lifetimes ---
  u16*  qbuf = (u16*)alloc((size_t)TOK * CDIM * 2);        // 32 MB phi(q) [bh][n][d]
  u16*  ktb  = (u16*)alloc((size_t)TOK * CDIM * 2);        // 32 MB phi(k) [bh][d][n]
  u16*  vtb  = (u16*)alloc((size_t)TOK * CDIM * 2);        // 32 MB v      [bh][d][n]
  u16*  abuf = (u16*)alloc((size_t)TOK * CDIM * 2);        // 32 MB attn out [b,n,c]
  // pkv/pks overlay abuf: dead before attn_kernel writes abuf
  float* pkv = (float*)abuf;                               // 8 MB  partial kv
  float* pks = (float*)(abuf + (size_t)8 * NBH * 4096 * 2);// 128KB partial ksum
  u16*  h3   = qbuf;  // 128 MB gelu out: reuses qbuf..abuf (all dead after proj)

  // weights fp32 -> bf16
  cvt_kernel<<<dim3(3 * CDIM * CDIM / 1024), 256, 0, stream>>>(qkvw, wq, 3 * CDIM * CDIM / 4);
  cvt_kernel<<<dim3(CDIM * CDIM / 1024),     256, 0, stream>>>(projw, wp, CDIM * CDIM / 4);
  cvt_kernel<<<dim3(HID * CDIM / 1024),      256, 0, stream>>>(fc1w, w1, HID * CDIM / 4);
  cvt_kernel<<<dim3(CDIM * HID / 1024),      256, 0, stream>>>(fc2w, w2, CDIM * HID / 4);

  ln_kernel<<<dim3(TOK), 256, 0, stream>>>(x, n1g, n1b, h12);
  gemm_bt<M_QKV><<<dim3(TOK / 128, 3 * CDIM / 128), 256, 0, stream>>>(
      h12, wq, CDIM, qbuf, ktb, vtb, nullptr, nullptr);
  kv_stage1<<<dim3(8, NBH), 256, 0, stream>>>(ktb, vtb, pkv, pks);
  kv_reduce<<<dim3(NBH), 256, 0, stream>>>(pkv, pks, kvt, ksm);
  attn_kernel<<<dim3(SEQ / 128, NBH), 256, 0, stream>>>(qbuf, kvt, ksm, abuf);
  gemm_bt<M_PROJ><<<dim3(TOK / 128, CDIM / 128), 256, 0, stream>>>(
      abuf, wp, CDIM, x2, nullptr, nullptr, projb, x);
  ln_kernel<<<dim3(TOK), 256, 0, stream>>>(x2, n2g, n2b, h12);
  gemm_bt<M_FC1><<<dim3(TOK / 128, HID / 128), 256, 0, stream>>>(
      h12, w1, CDIM, h3, nullptr, nullptr, fc1b, nullptr);
  gemm_bt<M_FC2><<<dim3(TOK / 128, CDIM / 128), 256, 0, stream>>>(
      h3, w2, HID, out, nullptr, nullptr, fc2b, x2);
}

// Round 5
// 935.501 us; speedup vs baseline: 1.0971x; 1.0650x over previous
//
#include <hip/hip_runtime.h>
#include <stdint.h>
#include <math.h>

// ---------------------------------------------------------------------------
// Fused transformer block w/ linear attention, bf16 MFMA GEMMs
//   B=4, N=4096 (TOK=16384 tokens), C=1024, H=16, d=64, HIDDEN=4096
// R5: 32x32x16 core + conflict-free LDS swizzle. global_load_lds forces
//     LDS dest = base+lane*16, so the swizzle permutes the GLOBAL chunk each
//     lane fetches: phys slot p <- logical(row=2a+(local>>2), ch=local&3),
//     a=p>>3, local=((p&7)-a)&7. Read of logical (row,c) at
//     a*64 + (((row&1)*4+c+a)&7)*8 halves. Slot usage across 64 lanes is
//     uniform (8 lanes/slot = min phases) vs 16/slot unswizzled.
// Workspace: 248.5 MiB, pkv/pks overlay abuf (disjoint lifetimes).
// ---------------------------------------------------------------------------

#define TOK   16384
#define CDIM  1024
#define NHEAD 16
#define HD    64
#define SEQ   4096
#define NBH   64
#define HID   4096

typedef unsigned short u16;
typedef __attribute__((ext_vector_type(8))) short bf16x8;
typedef __attribute__((ext_vector_type(4))) float f32x4;
typedef __attribute__((ext_vector_type(16))) float f32x16;
typedef __attribute__((ext_vector_type(4))) unsigned short u16x4;

__device__ __forceinline__ u16 f2bf(float f) {
  union { float f; uint32_t u; } c; c.f = f;
  uint32_t u = c.u;
  return (u16)((u + 0x7fffu + ((u >> 16) & 1u)) >> 16);  // RNE
}
__device__ __forceinline__ float bf2f(u16 h) {
  union { uint32_t u; float f; } c; c.u = ((uint32_t)h) << 16;
  return c.f;
}
__device__ __forceinline__ float gelu_fast(float u) {
  float y = 1.5957691216f * (u + 0.044715f * u * u * u);
  return u * __builtin_amdgcn_rcpf(1.0f + __expf(-y));
}

typedef const __attribute__((address_space(1))) uint32_t* gas_t;
typedef __attribute__((address_space(3))) uint32_t* las_t;
__device__ __forceinline__ void gl_lds16(const u16* g, u16* l) {
  __builtin_amdgcn_global_load_lds((gas_t)g, (las_t)l, 16, 0, 0);
}

// ---------------- weight convert fp32 -> bf16 (vectorized) -----------------
__global__ __launch_bounds__(256) void cvt_kernel(const float* __restrict__ in,
                                                  u16* __restrict__ out, int n4) {
  int i = blockIdx.x * 256 + threadIdx.x;
  if (i < n4) {
    float4 v = ((const float4*)in)[i];
    u16x4 o;
    o.x = f2bf(v.x); o.y = f2bf(v.y); o.z = f2bf(v.z); o.w = f2bf(v.w);
    ((u16x4*)out)[i] = o;
  }
}

// ---------------- LayerNorm (row of 1024), fp32 in -> bf16 out -------------
__global__ __launch_bounds__(256) void ln_kernel(const float* __restrict__ xin,
                                                 const float* __restrict__ g,
                                                 const float* __restrict__ b,
                                                 u16* __restrict__ out) {
  int row = blockIdx.x;
  int t = threadIdx.x;
  const float4* xr = (const float4*)(xin + (size_t)row * CDIM);
  float4 v = xr[t];
  float s  = v.x + v.y + v.z + v.w;
  float s2 = v.x * v.x + v.y * v.y + v.z * v.z + v.w * v.w;
#pragma unroll
  for (int off = 32; off > 0; off >>= 1) {
    s  += __shfl_down(s, off);
    s2 += __shfl_down(s2, off);
  }
  __shared__ float as_[4], bs_[4];
  if ((t & 63) == 0) { as_[t >> 6] = s; bs_[t >> 6] = s2; }
  __syncthreads();
  s  = as_[0] + as_[1] + as_[2] + as_[3];
  s2 = bs_[0] + bs_[1] + bs_[2] + bs_[3];
  float mu  = s * (1.0f / CDIM);
  float var = s2 * (1.0f / CDIM) - mu * mu;
  float rs  = rsqrtf(var + 1e-5f);
  float4 gv = ((const float4*)g)[t];
  float4 bv = ((const float4*)b)[t];
  u16x4 o;
  o.x = f2bf((v.x - mu) * rs * gv.x + bv.x);
  o.y = f2bf((v.y - mu) * rs * gv.y + bv.y);
  o.z = f2bf((v.z - mu) * rs * gv.z + bv.z);
  o.w = f2bf((v.w - mu) * rs * gv.w + bv.w);
  ((u16x4*)(out + (size_t)row * CDIM))[t] = o;
}

// ---------------- main GEMM: A[M,K] x W[N,K]^T, fused epilogues ------------
enum { M_QKV = 0, M_PROJ = 1, M_FC1 = 2, M_FC2 = 3 };

template <int MODE>
__global__ __launch_bounds__(256) void gemm_bt(const u16* __restrict__ A,
                                               const u16* __restrict__ W, int K,
                                               void* __restrict__ o0,
                                               void* __restrict__ o1,
                                               void* __restrict__ o2,
                                               const float* __restrict__ bias,
                                               const float* __restrict__ resid) {
  __shared__ __align__(16) u16 Als[128 * 32];
  __shared__ __align__(16) u16 Bls[128 * 32];
  const int t = threadIdx.x;
  const int l = t & 63, w = t >> 6;
  const int m0 = blockIdx.x * 128, n0 = blockIdx.y * 128;
  const int wm = (w >> 1) * 64, wn = (w & 1) * 64;
  const int ml = l & 31, kh = l >> 5;   // 32x32 frag: m|n = lane&31, k-half = lane>>5

  f32x16 acc[2][2] = {};

  const u16* Ab = A + (size_t)m0 * K;
  const u16* Wb = W + (size_t)n0 * K;

  // precompute swizzled staging source coords (uniform across k0)
  int srow[2], sch[2];
#pragma unroll
  for (int i = 0; i < 2; ++i) {
    int p = i * 256 + t;
    int a = p >> 3;                  // 128B line index (0..63)
    int local = ((p & 7) - a) & 7;   // logical (rowparity*4 + chunk)
    srow[i] = 2 * a + (local >> 2);
    sch[i]  = local & 3;
  }

  for (int k0 = 0; k0 < K; k0 += 32) {
#pragma unroll
    for (int i = 0; i < 2; ++i) {
      int p = i * 256 + t;
      gl_lds16(Ab + (size_t)srow[i] * K + k0 + sch[i] * 8, &Als[p * 8]);
      gl_lds16(Wb + (size_t)srow[i] * K + k0 + sch[i] * 8, &Bls[p * 8]);
    }
    __builtin_amdgcn_s_waitcnt(0);
    __syncthreads();
    bf16x8 af[2][2], bfv[2][2];
#pragma unroll
    for (int s = 0; s < 2; ++s)
#pragma unroll
      for (int i = 0; i < 2; ++i) {
        int ra = (wm + i * 32 + ml);         // A logical row in tile
        int aa = ra >> 1;
        int sa = (((ra & 1) << 2) + (s * 2 + kh) + aa) & 7;
        af[i][s]  = *(const bf16x8*)&Als[aa * 64 + sa * 8];
        int rb = (wn + i * 32 + ml);         // B logical row in tile
        int ab = rb >> 1;
        int sb = (((rb & 1) << 2) + (s * 2 + kh) + ab) & 7;
        bfv[i][s] = *(const bf16x8*)&Bls[ab * 64 + sb * 8];
      }
#pragma unroll
    for (int s = 0; s < 2; ++s)
#pragma unroll
      for (int i = 0; i < 2; ++i)
#pragma unroll
        for (int j = 0; j < 2; ++j)
          acc[i][j] = __builtin_amdgcn_mfma_f32_32x32x16_bf16(af[i][s], bfv[j][s],
                                                              acc[i][j], 0, 0, 0);
    __syncthreads();
  }

  // epilogue: D element col=lane&31, row=(r&3)+8*(r>>2)+4*(lane>>5), r in [0,16)
#pragma unroll
  for (int i = 0; i < 2; ++i) {
#pragma unroll
    for (int j = 0; j < 2; ++j) {
      int go = n0 + wn + j * 32 + ml;
#pragma unroll
      for (int r = 0; r < 16; ++r) {
        int gm = m0 + wm + i * 32 + (r & 3) + 8 * (r >> 2) + 4 * kh;
        float v = acc[i][j][r];
        if constexpr (MODE == M_QKV) {
          int sect = go >> 10, c = go & 1023;
          int h = c >> 6, dd = c & 63;
          int b = gm >> 12, n = gm & 4095;
          int bh = b * NHEAD + h;
          if (sect == 0) {          // q = elu(v)+1, layout [bh][n][d]
            float qv = v > 0.f ? v + 1.f : __expf(v);
            ((u16*)o0)[((size_t)bh * SEQ + n) * HD + dd] = f2bf(qv);
          } else if (sect == 1) {   // k = elu(v)+1, transposed [bh][d][n]
            float kk = v > 0.f ? v + 1.f : __expf(v);
            ((u16*)o1)[((size_t)bh * HD + dd) * SEQ + n] = f2bf(kk);
          } else {                  // v, transposed [bh][d][n]
            ((u16*)o2)[((size_t)bh * HD + dd) * SEQ + n] = f2bf(v);
          }
        } else if constexpr (MODE == M_PROJ) {
          ((float*)o0)[(size_t)gm * CDIM + go] = v + bias[go] + resid[(size_t)gm * CDIM + go];
        } else if constexpr (MODE == M_FC1) {
          float u = v + bias[go];
          ((u16*)o0)[(size_t)gm * HID + go] = f2bf(gelu_fast(u));
        } else {  // M_FC2
          ((float*)o0)[(size_t)gm * CDIM + go] = v + bias[go] + resid[(size_t)gm * CDIM + go];
        }
      }
    }
  }
}

// ------- kv state: partial kvT[e][d] = sum_n v[n,e]*k[n,d], per n-chunk -----
__global__ __launch_bounds__(256) void kv_stage1(const u16* __restrict__ kt,
                                                 const u16* __restrict__ vt,
                                                 float* __restrict__ pkv,
                                                 float* __restrict__ pks) {
  int ch = blockIdx.x, bh = blockIdx.y;
  int t = threadIdx.x, l = t & 63, w = t >> 6;
  int fr = l & 15, qq = l >> 4;
  int nb = ch * 512;
  const u16* vb = vt + (size_t)bh * HD * SEQ;
  const u16* kb = kt + (size_t)bh * HD * SEQ;
  int e0 = (w >> 1) * 32, d0 = (w & 1) * 32;
  f32x4 acc[2][2] = {};
  for (int kk = 0; kk < 512; kk += 32) {
    bf16x8 af[2], bfv[2];
#pragma unroll
    for (int i = 0; i < 2; ++i)
      af[i] = *(const bf16x8*)(vb + (size_t)(e0 + i * 16 + fr) * SEQ + nb + kk + qq * 8);
#pragma unroll
    for (int j = 0; j < 2; ++j)
      bfv[j] = *(const bf16x8*)(kb + (size_t)(d0 + j * 16 + fr) * SEQ + nb + kk + qq * 8);
#pragma unroll
    for (int i = 0; i < 2; ++i)
#pragma unroll
      for (int j = 0; j < 2; ++j)
        acc[i][j] = __builtin_amdgcn_mfma_f32_16x16x32_bf16(af[i], bfv[j], acc[i][j], 0, 0, 0);
  }
  float* pout = pkv + ((size_t)ch * NBH + bh) * 4096;
#pragma unroll
  for (int i = 0; i < 2; ++i)
#pragma unroll
    for (int j = 0; j < 2; ++j)
#pragma unroll
      for (int r = 0; r < 4; ++r) {
        int e = e0 + i * 16 + qq * 4 + r;
        int d = d0 + j * 16 + fr;
        pout[e * 64 + d] = acc[i][j][r];
      }
  // partial ksum over this n-chunk
  __shared__ float ksp[256];
  {
    int d = t & 63, part = t >> 6;
    const u16* kr = kb + (size_t)d * SEQ + nb + part * 128;
    float s = 0;
    for (int n = 0; n < 128; ++n) s += bf2f(kr[n]);
    ksp[t] = s;
  }
  __syncthreads();
  if (t < 64) {
    float s = ksp[t] + ksp[64 + t] + ksp[128 + t] + ksp[192 + t];
    pks[((size_t)ch * NBH + bh) * 64 + t] = s;
  }
}

__global__ __launch_bounds__(256) void kv_reduce(const float* __restrict__ pkv,
                                                 const float* __restrict__ pks,
                                                 u16* __restrict__ kvt,
                                                 float* __restrict__ ksm) {
  int bh = blockIdx.x, t = threadIdx.x;
  for (int ii = 0; ii < 16; ++ii) {
    int idx = ii * 256 + t;
    float s = 0;
#pragma unroll
    for (int c = 0; c < 8; ++c) s += pkv[((size_t)c * NBH + bh) * 4096 + idx];
    kvt[(size_t)bh * 4096 + idx] = f2bf(s);
  }
  if (t < 64) {
    float s = 0;
#pragma unroll
    for (int c = 0; c < 8; ++c) s += pks[((size_t)c * NBH + bh) * 64 + t];
    ksm[bh * 64 + t] = s;
  }
}

// ------- attn: out[n,e] = (sum_d q[n,d]*kvT[e,d]) * z[n], -> [b,n,c] bf16 ---
__global__ __launch_bounds__(256) void attn_kernel(const u16* __restrict__ qb,
                                                   const u16* __restrict__ kvt,
                                                   const float* __restrict__ ksm,
                                                   u16* __restrict__ ab) {
  int nblk = blockIdx.x, bh = blockIdx.y;
  int n0 = nblk * 128;
  int t = threadIdx.x, l = t & 63, w = t >> 6;
  int fr = l & 15, qq = l >> 4;
  __shared__ float ksh[64];
  __shared__ float part[256];
  __shared__ float zsh[128];
  if (t < 64) ksh[t] = ksm[bh * 64 + t];
  __syncthreads();
  {
    int rr = t >> 1, hf = t & 1;
    const u16* qr = qb + ((size_t)bh * SEQ + n0 + rr) * HD + hf * 32;
    float s = 0;
#pragma unroll
    for (int d = 0; d < 32; ++d) s += bf2f(qr[d]) * ksh[hf * 32 + d];
    part[t] = s;
  }
  __syncthreads();
  if (t < 128) zsh[t] = 1.0f / (part[2 * t] + part[2 * t + 1] + 1e-6f);
  __syncthreads();

  f32x4 acc[2][4] = {};
  const u16* qbase = qb + ((size_t)bh * SEQ + n0) * HD;
  const u16* kvb = kvt + (size_t)bh * 4096;
#pragma unroll
  for (int ks = 0; ks < 64; ks += 32) {
    bf16x8 af[2], bfv[4];
#pragma unroll
    for (int i = 0; i < 2; ++i)
      af[i] = *(const bf16x8*)(qbase + (size_t)(w * 32 + i * 16 + fr) * HD + ks + qq * 8);
#pragma unroll
    for (int j = 0; j < 4; ++j)
      bfv[j] = *(const bf16x8*)(kvb + (size_t)(j * 16 + fr) * HD + ks + qq * 8);
#pragma unroll
    for (int i = 0; i < 2; ++i)
#pragma unroll
      for (int j = 0; j < 4; ++j)
        acc[i][j] = __builtin_amdgcn_mfma_f32_16x16x32_bf16(af[i], bfv[j], acc[i][j], 0, 0, 0);
  }
  int b = bh >> 4, h = bh & 15;
#pragma unroll
  for (int i = 0; i < 2; ++i)
#pragma unroll
    for (int j = 0; j < 4; ++j)
#pragma unroll
      for (int r = 0; r < 4; ++r) {
        int rl = w * 32 + i * 16 + qq * 4 + r;
        int n = n0 + rl;
        int e = j * 16 + fr;
        float v = acc[i][j][r] * zsh[rl];
        ab[((size_t)(b * SEQ + n)) * CDIM + h * HD + e] = f2bf(v);
      }
}

// ---------------------------------------------------------------------------
extern "C" void kernel_launch(void* const* d_in, const int* in_sizes, int n_in,
                              void* d_out, int out_size, void* d_ws, size_t ws_size,
                              hipStream_t stream) {
  (void)in_sizes; (void)n_in; (void)out_size; (void)ws_size;
  const float* x     = (const float*)d_in[0];
  const float* n1g   = (const float*)d_in[1];
  const float* n1b   = (const float*)d_in[2];
  const float* qkvw  = (const float*)d_in[3];
  const float* projw = (const float*)d_in[4];
  const float* projb = (const float*)d_in[5];
  const float* n2g   = (const float*)d_in[6];
  const float* n2b   = (const float*)d_in[7];
  const float* fc1w  = (const float*)d_in[8];
  const float* fc1b  = (const float*)d_in[9];
  const float* fc2w  = (const float*)d_in[10];
  const float* fc2b  = (const float*)d_in[11];
  float* out = (float*)d_out;

  char* ws = (char*)d_ws;
  size_t off = 0;
  auto alloc = [&](size_t bytes) {
    void* p = ws + off;
    off += (bytes + 255) & ~(size_t)255;
    return p;
  };
  // --- persistent-lifetime allocations (248.5 MiB total incl. pool) ---
  u16*  wq   = (u16*)alloc((size_t)3 * CDIM * CDIM * 2);   // 6 MB  qkv_w bf16
  u16*  wp   = (u16*)alloc((size_t)CDIM * CDIM * 2);       // 2 MB  proj_w bf16
  u16*  w1   = (u16*)alloc((size_t)HID * CDIM * 2);        // 8 MB  fc1_w bf16
  u16*  w2   = (u16*)alloc((size_t)CDIM * HID * 2);        // 8 MB  fc2_w bf16
  u16*  kvt  = (u16*)alloc((size_t)NBH * 4096 * 2);        // 512KB kvT bf16
  float* ksm = (float*)alloc((size_t)NBH * 64 * 4);        // 16 KB ksum
  float* x2  = (float*)alloc((size_t)TOK * CDIM * 4);      // 64 MB x + attn (fp32)
  u16*  h12  = (u16*)alloc((size_t)TOK * CDIM * 2);        // 32 MB ln1 out, later ln2 out
  // --- 128 MB pool with overlaid lifetimes ---
  u16*  qbuf = (u16*)alloc((size_t)TOK * CDIM * 2);        // 32 MB phi(q) [bh][n][d]
  u16*  ktb  = (u16*)alloc((size_t)TOK * CDIM * 2);        // 32 MB phi(k) [bh][d][n]
  u16*  vtb  = (u16*)alloc((size_t)TOK * CDIM * 2);        // 32 MB v      [bh][d][n]
  u16*  abuf = (u16*)alloc((size_t)TOK * CDIM * 2);        // 32 MB attn out [b,n,c]
  // pkv/pks overlay abuf: dead before attn_kernel writes abuf
  float* pkv = (float*)abuf;                               // 8 MB  partial kv
  float* pks = (float*)(abuf + (size_t)8 * NBH * 4096 * 2);// 128KB partial ksum
  u16*  h3   = qbuf;  // 128 MB gelu out: reuses qbuf..abuf (all dead after proj)

  // weights fp32 -> bf16
  cvt_kernel<<<dim3(3 * CDIM * CDIM / 1024), 256, 0, stream>>>(qkvw, wq, 3 * CDIM * CDIM / 4);
  cvt_kernel<<<dim3(CDIM * CDIM / 1024),     256, 0, stream>>>(projw, wp, CDIM * CDIM / 4);
  cvt_kernel<<<dim3(HID * CDIM / 1024),      256, 0, stream>>>(fc1w, w1, HID * CDIM / 4);
  cvt_kernel<<<dim3(CDIM * HID / 1024),      256, 0, stream>>>(fc2w, w2, CDIM * HID / 4);

  ln_kernel<<<dim3(TOK), 256, 0, stream>>>(x, n1g, n1b, h12);
  gemm_bt<M_QKV><<<dim3(TOK / 128, 3 * CDIM / 128), 256, 0, stream>>>(
      h12, wq, CDIM, qbuf, ktb, vtb, nullptr, nullptr);
  kv_stage1<<<dim3(8, NBH), 256, 0, stream>>>(ktb, vtb, pkv, pks);
  kv_reduce<<<dim3(NBH), 256, 0, stream>>>(pkv, pks, kvt, ksm);
  attn_kernel<<<dim3(SEQ / 128, NBH), 256, 0, stream>>>(qbuf, kvt, ksm, abuf);
  gemm_bt<M_PROJ><<<dim3(TOK / 128, CDIM / 128), 256, 0, stream>>>(
      abuf, wp, CDIM, x2, nullptr, nullptr, projb, x);
  ln_kernel<<<dim3(TOK), 256, 0, stream>>>(x2, n2g, n2b, h12);
  gemm_bt<M_FC1><<<dim3(TOK / 128, HID / 128), 256, 0, stream>>>(
      h12, w1, CDIM, h3, nullptr, nullptr, fc1b, nullptr);
  gemm_bt<M_FC2><<<dim3(TOK / 128, CDIM / 128), 256, 0, stream>>>(
      h3, w2, HID, out, nullptr, nullptr, fc2b, x2);
}